// Round 3
// baseline (296.432 us; speedup 1.0000x reference)
//
#include <hip/hip_runtime.h>

// Problem constants (from reference): B=16, T=32, NP=8, NG=4, J=14, H=256
#define BT      512          // B*T
#define NP      8
#define NG      4
#define JNT     14
#define NCENTER 33554432     // B*T*H*H = 16*32*256*256
#define NBLK_CENTER 2048

// clang-native vector type: __builtin_nontemporal_load requires a real
// vector/scalar pointer, not HIP_vector_type<float,4>.
typedef float v4f __attribute__((ext_vector_type(4)));

__global__ void init_ws_kernel(float* __restrict__ ws) {
    if (threadIdx.x < 4) ws[threadIdx.x] = 0.0f;
}

__global__ __launch_bounds__(256, 4) void main_kernel(
    const float* __restrict__ hm,          // hor_heatmap (B,T,1,H,H) -> flat == gt_heatmap layout
    const float* __restrict__ hor_offset,  // (B,T,NP,2)
    const float* __restrict__ hor_bsize,   // (B,T,NP,4)
    const float* __restrict__ hor_center,  // (B,T,NP,2)
    const float* __restrict__ scores,      // (B,T,NP)
    const float* __restrict__ x_pose3d,    // (B,T,NP,J,3)
    const float* __restrict__ gt_hm,       // (B,T,H,H)
    const float* __restrict__ gt_wh,       // (B,T,NG,4)
    const float* __restrict__ gt_off,      // (B,T,NG,2)
    const float* __restrict__ gt_center,   // (B,T,NG,2)
    const float* __restrict__ gt_pose,     // (B,T,NG,J,3)
    float* __restrict__ ws)
{
    __shared__ float sC[32];    // box cost matrix [NP][NG]
    __shared__ float sCp[32];   // pose cost matrix [NP][NG]
    __shared__ float sv[8];     // reductions (vals): [0..3] box, [4..7] pose
    __shared__ int   sp[8];     // reductions (perm idx)

    const int blk = blockIdx.x;
    const int tid = threadIdx.x;

    if (blk >= BT) {
        // ---- center loss: sum of squared diffs, v4f grid-stride, ILP x4 ----
        const int cb = blk - BT;
        const v4f* a = (const v4f*)hm;
        const v4f* b = (const v4f*)gt_hm;
        const int n4 = NCENTER / 4;
        const int stride = NBLK_CENTER * 256;
        int i = cb * 256 + tid;
        float s0 = 0.0f, s1 = 0.0f, s2 = 0.0f, s3 = 0.0f;
        for (; i + 3 * stride < n4; i += 4 * stride) {
            v4f x0 = __builtin_nontemporal_load(&a[i]);
            v4f x1 = __builtin_nontemporal_load(&a[i + stride]);
            v4f x2 = __builtin_nontemporal_load(&a[i + 2 * stride]);
            v4f x3 = __builtin_nontemporal_load(&a[i + 3 * stride]);
            v4f y0 = __builtin_nontemporal_load(&b[i]);
            v4f y1 = __builtin_nontemporal_load(&b[i + stride]);
            v4f y2 = __builtin_nontemporal_load(&b[i + 2 * stride]);
            v4f y3 = __builtin_nontemporal_load(&b[i + 3 * stride]);
            v4f d0 = x0 - y0, d1 = x1 - y1, d2 = x2 - y2, d3 = x3 - y3;
            s0 += d0.x * d0.x + d0.y * d0.y + d0.z * d0.z + d0.w * d0.w;
            s1 += d1.x * d1.x + d1.y * d1.y + d1.z * d1.z + d1.w * d1.w;
            s2 += d2.x * d2.x + d2.y * d2.y + d2.z * d2.z + d2.w * d2.w;
            s3 += d3.x * d3.x + d3.y * d3.y + d3.z * d3.z + d3.w * d3.w;
        }
        for (; i < n4; i += stride) {
            v4f x = a[i];
            v4f y = b[i];
            v4f d = x - y;
            s0 += d.x * d.x + d.y * d.y + d.z * d.z + d.w * d.w;
        }
        float s = (s0 + s1) + (s2 + s3);
        #pragma unroll
        for (int o = 32; o > 0; o >>= 1) s += __shfl_down(s, o);
        const int lane = tid & 63, w = tid >> 6;
        if (lane == 0) sv[w] = s;
        __syncthreads();
        if (tid == 0) atomicAdd(&ws[0], sv[0] + sv[1] + sv[2] + sv[3]);
        return;
    }

    // ---- Hungarian matching for one (b,t) cell ----
    const int c = blk;                             // 0..511
    const float* pc = hor_center + c * (NP * 2);
    const float* gc = gt_center  + c * (NG * 2);
    const float* sc = scores     + c * NP;
    const float* po = hor_offset + c * (NP * 2);
    const float* go = gt_off     + c * (NG * 2);
    const float* ps = hor_bsize  + c * (NP * 4);
    const float* gs = gt_wh      + c * (NG * 4);
    const float* pp = x_pose3d   + c * (NP * JNT * 3);
    const float* gp = gt_pose    + c * (NG * JNT * 3);

    if (tid < 32) {
        const int i = tid >> 2;   // pred row 0..7
        const int j = tid & 3;    // gt col 0..3
        float dx = pc[i * 2 + 0] - gc[j * 2 + 0];
        float dy = pc[i * 2 + 1] - gc[j * 2 + 1];
        sC[i * 4 + j] = sqrtf(dx * dx + dy * dy) - sc[i];
        float acc = 0.0f;
        const float* ai = pp + i * (JNT * 3);
        const float* gj = gp + j * (JNT * 3);
        #pragma unroll
        for (int k = 0; k < JNT * 3; k++) {
            float d = ai[k] - gj[k];
            acc += d * d;
        }
        sCp[i * 4 + j] = sqrtf(acc);
    }
    __syncthreads();

    // enumerate all 8^4 tuples in lexicographic order; skip non-injective.
    // This ordering (restricted to injective tuples) matches
    // itertools.permutations(range(8), 4); ties break to lowest index.
    float bv = 1e30f, bv2 = 1e30f;
    int bp = 0x7fffffff, bp2 = 0x7fffffff;
    for (int p = tid; p < 4096; p += 256) {
        const int i0 = (p >> 9) & 7, i1 = (p >> 6) & 7, i2 = (p >> 3) & 7, i3 = p & 7;
        if (i0 == i1 || i0 == i2 || i0 == i3 || i1 == i2 || i1 == i3 || i2 == i3) continue;
        float t  = sC [i0 * 4 + 0] + sC [i1 * 4 + 1] + sC [i2 * 4 + 2] + sC [i3 * 4 + 3];
        float t2 = sCp[i0 * 4 + 0] + sCp[i1 * 4 + 1] + sCp[i2 * 4 + 2] + sCp[i3 * 4 + 3];
        if (t  < bv)  { bv  = t;  bp  = p; }   // strictly-less keeps lowest p on ties
        if (t2 < bv2) { bv2 = t2; bp2 = p; }
    }
    #pragma unroll
    for (int o = 32; o > 0; o >>= 1) {
        float v2 = __shfl_down(bv, o);  int p2 = __shfl_down(bp, o);
        if (v2 < bv  || (v2 == bv  && p2 < bp))  { bv  = v2; bp  = p2; }
        float w2 = __shfl_down(bv2, o); int q2 = __shfl_down(bp2, o);
        if (w2 < bv2 || (w2 == bv2 && q2 < bp2)) { bv2 = w2; bp2 = q2; }
    }
    const int lane = tid & 63, w = tid >> 6;
    if (lane == 0) { sv[w] = bv; sp[w] = bp; sv[4 + w] = bv2; sp[4 + w] = bp2; }
    __syncthreads();

    if (tid == 0) {
        for (int k = 1; k < 4; k++) {
            if (sv[k] < sv[0] || (sv[k] == sv[0] && sp[k] < sp[0])) { sv[0] = sv[k]; sp[0] = sp[k]; }
            if (sv[4 + k] < sv[4] || (sv[4 + k] == sv[4] && sp[4 + k] < sp[4])) { sv[4] = sv[4 + k]; sp[4] = sp[4 + k]; }
        }
        const int pb = sp[0];   // best box perm (packed i0..i3)
        const int pq = sp[4];   // best pose perm
        float off = 0.0f, size = 0.0f, pose = 0.0f;
        #pragma unroll
        for (int jj = 0; jj < 4; jj++) {
            const int r = (pb >> (9 - 3 * jj)) & 7;
            off += 0.5f * (fabsf(po[r * 2 + 0] - go[jj * 2 + 0]) +
                           fabsf(po[r * 2 + 1] - go[jj * 2 + 1]));
            size += 0.25f * (fabsf(ps[r * 4 + 0] - gs[jj * 4 + 0]) +
                             fabsf(ps[r * 4 + 1] - gs[jj * 4 + 1]) +
                             fabsf(ps[r * 4 + 2] - gs[jj * 4 + 2]) +
                             fabsf(ps[r * 4 + 3] - gs[jj * 4 + 3]));
            const int r2 = (pq >> (9 - 3 * jj)) & 7;
            const float* ai = pp + r2 * (JNT * 3);
            const float* gj = gp + jj * (JNT * 3);
            #pragma unroll 1
            for (int k = 0; k < JNT * 3; k++) {
                float d = ai[k] - gj[k];
                pose += d * d;
            }
        }
        atomicAdd(&ws[1], off);
        atomicAdd(&ws[2], size);
        atomicAdd(&ws[3], pose);
    }
}

__global__ void final_kernel(const float* __restrict__ ws, float* __restrict__ out) {
    // total = center_mean + off_sum/BT + size_sum/BT + pose_sum/(BT*NP*J)
    out[0] = ws[0] * (1.0f / (float)NCENTER)
           + (ws[1] + ws[2]) * (1.0f / (float)BT)
           + ws[3] * (1.0f / (float)(BT * NP * JNT));
}

extern "C" void kernel_launch(void* const* d_in, const int* in_sizes, int n_in,
                              void* d_out, int out_size, void* d_ws, size_t ws_size,
                              hipStream_t stream) {
    const float* hm         = (const float*)d_in[0];
    const float* hor_offset = (const float*)d_in[1];
    const float* hor_bsize  = (const float*)d_in[2];
    const float* hor_center = (const float*)d_in[3];
    const float* scores     = (const float*)d_in[4];
    const float* x_pose3d   = (const float*)d_in[5];
    const float* gt_hm      = (const float*)d_in[6];
    const float* gt_wh      = (const float*)d_in[7];
    const float* gt_off     = (const float*)d_in[8];
    const float* gt_center  = (const float*)d_in[9];
    const float* gt_pose    = (const float*)d_in[10];
    float* ws  = (float*)d_ws;
    float* out = (float*)d_out;

    init_ws_kernel<<<1, 64, 0, stream>>>(ws);
    main_kernel<<<BT + NBLK_CENTER, 256, 0, stream>>>(
        hm, hor_offset, hor_bsize, hor_center, scores, x_pose3d,
        gt_hm, gt_wh, gt_off, gt_center, gt_pose, ws);
    final_kernel<<<1, 1, 0, stream>>>(ws, out);
}

// Round 4
// 270.014 us; speedup vs baseline: 1.0978x; 1.0978x over previous
//
#include <hip/hip_runtime.h>

// Problem constants (from reference): B=16, T=32, NP=8, NG=4, J=14, H=256
#define BT      512          // B*T
#define NP      8
#define NG      4
#define JNT     14
#define NCENTER 33554432     // B*T*H*H = 16*32*256*256
#define NBLK_CENTER 2048

// ws layout (floats): [0..2047] center partials per center-block
//                     [2048..2559] off per cell, [2560..3071] size, [3072..3583] pose
// ws is poisoned by the harness between iterations; we only read what we wrote
// this launch (write-then-read within the same launch sequence), so no init pass.

// clang-native vector type: __builtin_nontemporal_load requires a real
// vector/scalar pointer, not HIP_vector_type<float,4>.
typedef float v4f __attribute__((ext_vector_type(4)));

__global__ __launch_bounds__(256, 4) void main_kernel(
    const float* __restrict__ hm,          // hor_heatmap (B,T,1,H,H) -> flat == gt_heatmap layout
    const float* __restrict__ hor_offset,  // (B,T,NP,2)
    const float* __restrict__ hor_bsize,   // (B,T,NP,4)
    const float* __restrict__ hor_center,  // (B,T,NP,2)
    const float* __restrict__ scores,      // (B,T,NP)
    const float* __restrict__ x_pose3d,    // (B,T,NP,J,3)
    const float* __restrict__ gt_hm,       // (B,T,H,H)
    const float* __restrict__ gt_wh,       // (B,T,NG,4)
    const float* __restrict__ gt_off,      // (B,T,NG,2)
    const float* __restrict__ gt_center,   // (B,T,NG,2)
    const float* __restrict__ gt_pose,     // (B,T,NG,J,3)
    float* __restrict__ ws)
{
    __shared__ float sC[32];    // box cost matrix [NP][NG]
    __shared__ float sCp[32];   // pose cost matrix [NP][NG]
    __shared__ float sv[8];     // reductions (vals): [0..3] box, [4..7] pose
    __shared__ int   sp[8];     // reductions (perm idx)

    const int blk = blockIdx.x;
    const int tid = threadIdx.x;

    if (blk >= BT) {
        // ---- center loss: sum of squared diffs, v4f grid-stride, ILP x4 ----
        const int cb = blk - BT;
        const v4f* a = (const v4f*)hm;
        const v4f* b = (const v4f*)gt_hm;
        const int n4 = NCENTER / 4;
        const int stride = NBLK_CENTER * 256;
        int i = cb * 256 + tid;
        float s0 = 0.0f, s1 = 0.0f, s2 = 0.0f, s3 = 0.0f;
        for (; i + 3 * stride < n4; i += 4 * stride) {
            v4f x0 = __builtin_nontemporal_load(&a[i]);
            v4f x1 = __builtin_nontemporal_load(&a[i + stride]);
            v4f x2 = __builtin_nontemporal_load(&a[i + 2 * stride]);
            v4f x3 = __builtin_nontemporal_load(&a[i + 3 * stride]);
            v4f y0 = __builtin_nontemporal_load(&b[i]);
            v4f y1 = __builtin_nontemporal_load(&b[i + stride]);
            v4f y2 = __builtin_nontemporal_load(&b[i + 2 * stride]);
            v4f y3 = __builtin_nontemporal_load(&b[i + 3 * stride]);
            v4f d0 = x0 - y0, d1 = x1 - y1, d2 = x2 - y2, d3 = x3 - y3;
            s0 += d0.x * d0.x + d0.y * d0.y + d0.z * d0.z + d0.w * d0.w;
            s1 += d1.x * d1.x + d1.y * d1.y + d1.z * d1.z + d1.w * d1.w;
            s2 += d2.x * d2.x + d2.y * d2.y + d2.z * d2.z + d2.w * d2.w;
            s3 += d3.x * d3.x + d3.y * d3.y + d3.z * d3.z + d3.w * d3.w;
        }
        for (; i < n4; i += stride) {
            v4f x = a[i];
            v4f y = b[i];
            v4f d = x - y;
            s0 += d.x * d.x + d.y * d.y + d.z * d.z + d.w * d.w;
        }
        float s = (s0 + s1) + (s2 + s3);
        #pragma unroll
        for (int o = 32; o > 0; o >>= 1) s += __shfl_down(s, o);
        const int lane = tid & 63, w = tid >> 6;
        if (lane == 0) sv[w] = s;
        __syncthreads();
        if (tid == 0) ws[cb] = sv[0] + sv[1] + sv[2] + sv[3];   // deterministic partial
        return;
    }

    // ---- Hungarian matching for one (b,t) cell ----
    const int c = blk;                             // 0..511
    const float* pc = hor_center + c * (NP * 2);
    const float* gc = gt_center  + c * (NG * 2);
    const float* sc = scores     + c * NP;
    const float* po = hor_offset + c * (NP * 2);
    const float* go = gt_off     + c * (NG * 2);
    const float* ps = hor_bsize  + c * (NP * 4);
    const float* gs = gt_wh      + c * (NG * 4);
    const float* pp = x_pose3d   + c * (NP * JNT * 3);
    const float* gp = gt_pose    + c * (NG * JNT * 3);

    if (tid < 32) {
        const int i = tid >> 2;   // pred row 0..7
        const int j = tid & 3;    // gt col 0..3
        float dx = pc[i * 2 + 0] - gc[j * 2 + 0];
        float dy = pc[i * 2 + 1] - gc[j * 2 + 1];
        sC[i * 4 + j] = sqrtf(dx * dx + dy * dy) - sc[i];
        float acc = 0.0f;
        const float* ai = pp + i * (JNT * 3);
        const float* gj = gp + j * (JNT * 3);
        #pragma unroll
        for (int k = 0; k < JNT * 3; k++) {
            float d = ai[k] - gj[k];
            acc += d * d;
        }
        sCp[i * 4 + j] = sqrtf(acc);
    }
    __syncthreads();

    // enumerate all 8^4 tuples in lexicographic order; skip non-injective.
    // This ordering (restricted to injective tuples) matches
    // itertools.permutations(range(8), 4); ties break to lowest index.
    float bv = 1e30f, bv2 = 1e30f;
    int bp = 0x7fffffff, bp2 = 0x7fffffff;
    for (int p = tid; p < 4096; p += 256) {
        const int i0 = (p >> 9) & 7, i1 = (p >> 6) & 7, i2 = (p >> 3) & 7, i3 = p & 7;
        if (i0 == i1 || i0 == i2 || i0 == i3 || i1 == i2 || i1 == i3 || i2 == i3) continue;
        float t  = sC [i0 * 4 + 0] + sC [i1 * 4 + 1] + sC [i2 * 4 + 2] + sC [i3 * 4 + 3];
        float t2 = sCp[i0 * 4 + 0] + sCp[i1 * 4 + 1] + sCp[i2 * 4 + 2] + sCp[i3 * 4 + 3];
        if (t  < bv)  { bv  = t;  bp  = p; }   // strictly-less keeps lowest p on ties
        if (t2 < bv2) { bv2 = t2; bp2 = p; }
    }
    #pragma unroll
    for (int o = 32; o > 0; o >>= 1) {
        float v2 = __shfl_down(bv, o);  int p2 = __shfl_down(bp, o);
        if (v2 < bv  || (v2 == bv  && p2 < bp))  { bv  = v2; bp  = p2; }
        float w2 = __shfl_down(bv2, o); int q2 = __shfl_down(bp2, o);
        if (w2 < bv2 || (w2 == bv2 && q2 < bp2)) { bv2 = w2; bp2 = q2; }
    }
    const int lane = tid & 63, w = tid >> 6;
    if (lane == 0) { sv[w] = bv; sp[w] = bp; sv[4 + w] = bv2; sp[4 + w] = bp2; }
    __syncthreads();

    if (tid == 0) {
        for (int k = 1; k < 4; k++) {
            if (sv[k] < sv[0] || (sv[k] == sv[0] && sp[k] < sp[0])) { sv[0] = sv[k]; sp[0] = sp[k]; }
            if (sv[4 + k] < sv[4] || (sv[4 + k] == sv[4] && sp[4 + k] < sp[4])) { sv[4] = sv[4 + k]; sp[4] = sp[4 + k]; }
        }
        const int pb = sp[0];   // best box perm (packed i0..i3)
        const int pq = sp[4];   // best pose perm
        float off = 0.0f, size = 0.0f, pose = 0.0f;
        #pragma unroll
        for (int jj = 0; jj < 4; jj++) {
            const int r = (pb >> (9 - 3 * jj)) & 7;
            off += 0.5f * (fabsf(po[r * 2 + 0] - go[jj * 2 + 0]) +
                           fabsf(po[r * 2 + 1] - go[jj * 2 + 1]));
            size += 0.25f * (fabsf(ps[r * 4 + 0] - gs[jj * 4 + 0]) +
                             fabsf(ps[r * 4 + 1] - gs[jj * 4 + 1]) +
                             fabsf(ps[r * 4 + 2] - gs[jj * 4 + 2]) +
                             fabsf(ps[r * 4 + 3] - gs[jj * 4 + 3]));
            const int r2 = (pq >> (9 - 3 * jj)) & 7;
            const float* ai = pp + r2 * (JNT * 3);
            const float* gj = gp + jj * (JNT * 3);
            #pragma unroll 1
            for (int k = 0; k < JNT * 3; k++) {
                float d = ai[k] - gj[k];
                pose += d * d;
            }
        }
        ws[2048 + c] = off;     // deterministic per-cell partials
        ws[2560 + c] = size;
        ws[3072 + c] = pose;
    }
}

__global__ __launch_bounds__(256) void final_kernel(const float* __restrict__ ws,
                                                    float* __restrict__ out) {
    __shared__ float sred[4][4];
    const int tid = threadIdx.x;
    // center partials: 2048 entries, 8 per thread
    float c = 0.0f;
    #pragma unroll
    for (int i = 0; i < 8; i++) c += ws[tid + i * 256];
    // per-cell partials: 512 entries each, 2 per thread
    float o = ws[2048 + tid] + ws[2048 + 256 + tid];
    float s = ws[2560 + tid] + ws[2560 + 256 + tid];
    float p = ws[3072 + tid] + ws[3072 + 256 + tid];
    #pragma unroll
    for (int off2 = 32; off2 > 0; off2 >>= 1) {
        c += __shfl_down(c, off2);
        o += __shfl_down(o, off2);
        s += __shfl_down(s, off2);
        p += __shfl_down(p, off2);
    }
    const int lane = tid & 63, w = tid >> 6;
    if (lane == 0) { sred[0][w] = c; sred[1][w] = o; sred[2][w] = s; sred[3][w] = p; }
    __syncthreads();
    if (tid == 0) {
        float C = sred[0][0] + sred[0][1] + sred[0][2] + sred[0][3];
        float O = sred[1][0] + sred[1][1] + sred[1][2] + sred[1][3];
        float S = sred[2][0] + sred[2][1] + sred[2][2] + sred[2][3];
        float P = sred[3][0] + sred[3][1] + sred[3][2] + sred[3][3];
        // total = center_mean + off_sum/BT + size_sum/BT + pose_sum/(BT*NP*J)
        out[0] = C * (1.0f / (float)NCENTER)
               + (O + S) * (1.0f / (float)BT)
               + P * (1.0f / (float)(BT * NP * JNT));
    }
}

extern "C" void kernel_launch(void* const* d_in, const int* in_sizes, int n_in,
                              void* d_out, int out_size, void* d_ws, size_t ws_size,
                              hipStream_t stream) {
    const float* hm         = (const float*)d_in[0];
    const float* hor_offset = (const float*)d_in[1];
    const float* hor_bsize  = (const float*)d_in[2];
    const float* hor_center = (const float*)d_in[3];
    const float* scores     = (const float*)d_in[4];
    const float* x_pose3d   = (const float*)d_in[5];
    const float* gt_hm      = (const float*)d_in[6];
    const float* gt_wh      = (const float*)d_in[7];
    const float* gt_off     = (const float*)d_in[8];
    const float* gt_center  = (const float*)d_in[9];
    const float* gt_pose    = (const float*)d_in[10];
    float* ws  = (float*)d_ws;
    float* out = (float*)d_out;

    main_kernel<<<BT + NBLK_CENTER, 256, 0, stream>>>(
        hm, hor_offset, hor_bsize, hor_center, scores, x_pose3d,
        gt_hm, gt_wh, gt_off, gt_center, gt_pose, ws);
    final_kernel<<<1, 256, 0, stream>>>(ws, out);
}